// Round 4
// baseline (18029.736 us; speedup 1.0000x reference)
//
#include <hip/hip_runtime.h>

// Decoder: 2-layer LSTM (H=256), T=512, B=256, scalar output feedback.
// Round 4: MFMA-based. 16 blocks x 1024 threads, M=16 batch per block.
// Weights fp16, pre-packed into mfma_f32_16x16x32_f16 A-fragment order and
// streamed global->VGPR (no LDS round trip). h exchanged via small LDS
// buffers as B-fragments. Cell state fp32 in registers (gates i/f/g/o for a
// cell land in the same lane: D row=(lane>>4)*4+reg, col=lane&15=batch).

namespace {

typedef _Float16 v8h __attribute__((ext_vector_type(8)));
typedef float v4f __attribute__((ext_vector_type(4)));

constexpr int kB = 256, kT = 512, kH = 256;
constexpr int kStride = 264;  // halves per batch row of h-buffer (+8 pad)
constexpr int kFragsPerMat = 512 * 64;               // (64 mtiles * 8 ktiles) * 64 lanes
constexpr size_t kWsNeeded = 3 * (size_t)kFragsPerMat * sizeof(v8h);  // 1.5 MB

__device__ __forceinline__ float fsig(float v) {
  return __builtin_amdgcn_rcpf(1.f + __expf(-v));
}
__device__ __forceinline__ float ftanh(float v) {
  return 1.f - 2.f * __builtin_amdgcn_rcpf(1.f + __expf(2.f * v));
}

// Pack W (1024x256 fp32 row-major) into A-fragment order, fp16:
// frag f = mtile*8 + kt; lane holds W[mtile*16 + (lane&15)][kt*32 + (lane>>4)*8 + j]
__global__ __launch_bounds__(256) void pack_frag(const float* __restrict__ s0,
                                                 const float* __restrict__ s1,
                                                 const float* __restrict__ s2,
                                                 v8h* __restrict__ dst) {
  int idx = blockIdx.x * 256 + threadIdx.x;  // 0 .. 98303
  int lane = idx & 63;
  int f = (idx >> 6) & 511;
  int mat = idx >> 15;
  int row = (f >> 3) * 16 + (lane & 15);
  int k0 = (f & 7) * 32 + (lane >> 4) * 8;
  const float* src = (mat == 0 ? s0 : mat == 1 ? s1 : s2) + row * 256 + k0;
  v8h v;
#pragma unroll
  for (int j = 0; j < 8; ++j) v[j] = (_Float16)src[j];
  dst[idx] = v;
}

__global__ __launch_bounds__(1024) void decoder_mfma(
    const float* __restrict__ seq, const float* __restrict__ z,
    const float* __restrict__ wih0, const float* __restrict__ bih0,
    const float* __restrict__ bhh0, const float* __restrict__ bih1,
    const float* __restrict__ bhh1, const float* __restrict__ wout,
    const float* __restrict__ bout, const v8h* __restrict__ pack,
    float* __restrict__ loss_out) {
  __shared__ _Float16 hbuf[4][16 * kStride];  // h0[2], h1[2] : 33.8 KB
  __shared__ float lb0[1024], lw0[1024], lb1[1024];
  __shared__ float lwout[256];
  __shared__ float lspred[16 * 16];  // [wave][batch]
  __shared__ float lx[16];

  const int tid = threadIdx.x;
  const int w = tid >> 6;       // wave 0..15 -> h-rows [16w,16w+16)
  const int l = tid & 63;
  const int n = l & 15;         // batch lane (B-frag col / D col)
  const int kg = l >> 4;        // k-group (inputs) / row-group (outputs)
  const int b0 = blockIdx.x * 16;

  lb0[tid] = bih0[tid] + bhh0[tid];
  lw0[tid] = wih0[tid];
  lb1[tid] = bih1[tid] + bhh1[tid];
  if (tid < 256) lwout[tid] = wout[tid];
  if (tid < 16) lx[tid] = 0.f;
  for (int i = tid; i < 16 * 256; i += 1024) {
    int bb = i >> 8, k = i & 255;
    _Float16 hv = (_Float16)z[(size_t)(b0 + bb) * kH + k];
    hbuf[0][bb * kStride + k] = hv;  // h0 parity 0
    hbuf[2][bb * kStride + k] = hv;  // h1 parity 0
  }
  const int rb0 = w * 16 + kg * 4;  // h-row base for this lane's D rows
  float c0[4], c1[4];
#pragma unroll
  for (int r = 0; r < 4; ++r) {
    float zv = z[(size_t)(b0 + n) * kH + rb0 + r];
    c0[r] = zv;
    c1[r] = zv;
  }
  const float bo = bout[0];
  float lacc = 0.f;
  __syncthreads();

  const v8h* a0 = pack;                     // Whh0
  const v8h* a1 = pack + kFragsPerMat;      // Wih1
  const v8h* a2 = pack + 2 * kFragsPerMat;  // Whh1
  const int boff = n * kStride + kg * 8;    // B-frag base offset (halves)

  for (int t = 0; t < kT; ++t) {
    const int p = t & 1;
    const _Float16* h0r = hbuf[p];
    _Float16* h0w = hbuf[1 - p];
    const _Float16* h1r = hbuf[2 + p];
    _Float16* h1w = hbuf[3 - p];

    // ---- layer 0: gates = Whh0 @ h0 (+ x*wih0 + bias) ----
    v8h bf[8];
#pragma unroll
    for (int kt = 0; kt < 8; ++kt)
      bf[kt] = *(const v8h*)&h0r[boff + kt * 32];
    v4f ac[4];
#pragma unroll
    for (int q = 0; q < 4; ++q) {
      v4f acc = {0.f, 0.f, 0.f, 0.f};
      const v8h* ap = a0 + ((q * 16 + w) * 8) * 64 + l;
#pragma unroll
      for (int kt = 0; kt < 8; ++kt)
        acc = __builtin_amdgcn_mfma_f32_16x16x32_f16(ap[kt * 64], bf[kt], acc, 0, 0, 0);
      ac[q] = acc;
    }
    {
      float x = lx[n];
#pragma unroll
      for (int r = 0; r < 4; ++r) {
        int rb = rb0 + r;
        float pi = ac[0][r] + lb0[rb] + x * lw0[rb];
        float pf = ac[1][r] + lb0[256 + rb] + x * lw0[256 + rb];
        float pg = ac[2][r] + lb0[512 + rb] + x * lw0[512 + rb];
        float po = ac[3][r] + lb0[768 + rb] + x * lw0[768 + rb];
        c0[r] = fsig(pf) * c0[r] + fsig(pi) * ftanh(pg);
        float hn = fsig(po) * ftanh(c0[r]);
        h0w[n * kStride + rb] = (_Float16)hn;
      }
    }
    __syncthreads();  // barrier 1: h0(t) slices visible

    // ---- layer 1: gates = Wih1 @ h0new + Whh1 @ h1old + bias ----
#pragma unroll
    for (int kt = 0; kt < 8; ++kt)
      bf[kt] = *(const v8h*)&h0w[boff + kt * 32];
#pragma unroll
    for (int q = 0; q < 4; ++q) {
      v4f acc = {0.f, 0.f, 0.f, 0.f};
      const v8h* ap = a1 + ((q * 16 + w) * 8) * 64 + l;
#pragma unroll
      for (int kt = 0; kt < 8; ++kt)
        acc = __builtin_amdgcn_mfma_f32_16x16x32_f16(ap[kt * 64], bf[kt], acc, 0, 0, 0);
      ac[q] = acc;
    }
#pragma unroll
    for (int kt = 0; kt < 8; ++kt)
      bf[kt] = *(const v8h*)&h1r[boff + kt * 32];
#pragma unroll
    for (int q = 0; q < 4; ++q) {
      v4f acc = ac[q];
      const v8h* ap = a2 + ((q * 16 + w) * 8) * 64 + l;
#pragma unroll
      for (int kt = 0; kt < 8; ++kt)
        acc = __builtin_amdgcn_mfma_f32_16x16x32_f16(ap[kt * 64], bf[kt], acc, 0, 0, 0);
      ac[q] = acc;
    }
    {
      float pp = 0.f;
#pragma unroll
      for (int r = 0; r < 4; ++r) {
        int rb = rb0 + r;
        float pi = ac[0][r] + lb1[rb];
        float pf = ac[1][r] + lb1[256 + rb];
        float pg = ac[2][r] + lb1[512 + rb];
        float po = ac[3][r] + lb1[768 + rb];
        c1[r] = fsig(pf) * c1[r] + fsig(pi) * ftanh(pg);
        float hn = fsig(po) * ftanh(c1[r]);
        h1w[n * kStride + rb] = (_Float16)hn;
        pp = fmaf(hn, lwout[rb], pp);
      }
      pp += __shfl_xor(pp, 16);
      pp += __shfl_xor(pp, 32);
      if (l < 16) lspred[w * 16 + l] = pp;  // wave-partial for batch l
    }
    __syncthreads();  // barrier 2: h1(t) + pred partials visible

    if (tid < 16) {
      float pred = bo;
#pragma unroll
      for (int ww = 0; ww < 16; ++ww) pred += lspred[ww * 16 + tid];
      float d = seq[(size_t)(b0 + tid) * kT + t] - pred;
      lacc = fmaf(d, d, lacc);
      lx[tid] = pred;
    }
    __syncthreads();  // barrier 3: x(t) stable before next step's use
  }

  if (tid < 16) atomicAdd(loss_out, lacc * (1.0f / ((float)kB * (float)kT)));
}

// ---------------- fallback (round-1 structure, no workspace needed) --------
__global__ __launch_bounds__(1024) void decoder_fallback(
    const float* __restrict__ seq, const float* __restrict__ z,
    const float* __restrict__ wih0, const float* __restrict__ bih0,
    const float* __restrict__ bhh0, const float* __restrict__ whh0,
    const float* __restrict__ wih1, const float* __restrict__ whh1,
    const float* __restrict__ bih1, const float* __restrict__ bhh1,
    const float* __restrict__ wout, const float* __restrict__ bout,
    float* __restrict__ loss_out) {
  __shared__ float h0s[kH], h1s[kH], g4[1024];
  __shared__ float xs_s;
  const int tid = threadIdx.x;
  const int b = blockIdx.x;
  float c0r = 0.f, c1r = 0.f;
  if (tid < kH) {
    float zv = z[b * kH + tid];
    h0s[tid] = zv; h1s[tid] = zv; c0r = zv; c1r = zv;
  }
  if (tid == 0) xs_s = 0.f;
  const float wih0_j = wih0[tid];
  const float bias0_j = bih0[tid] + bhh0[tid];
  const float bias1_j = bih1[tid] + bhh1[tid];
  const float wout_r = (tid < kH) ? wout[tid] : 0.f;
  const float bo = bout[0];
  float lacc = 0.f;
  __syncthreads();
  for (int t = 0; t < kT; ++t) {
    float a0 = fmaf(xs_s, wih0_j, bias0_j);
    for (int k = 0; k < kH; ++k) a0 = fmaf(whh0[tid * kH + k], h0s[k], a0);
    g4[tid] = a0;
    __syncthreads();
    if (tid < kH) {
      float ig = fsig(g4[tid]), fg = fsig(g4[tid + 256]);
      float gg = ftanh(g4[tid + 512]), og = fsig(g4[tid + 768]);
      c0r = fmaf(fg, c0r, ig * gg);
      h0s[tid] = og * ftanh(c0r);
    }
    __syncthreads();
    float a1 = bias1_j;
    for (int k = 0; k < kH; ++k) a1 = fmaf(wih1[tid * kH + k], h0s[k], a1);
    for (int k = 0; k < kH; ++k) a1 = fmaf(whh1[tid * kH + k], h1s[k], a1);
    g4[tid] = a1;
    __syncthreads();
    if (tid < kH) {
      float ig = fsig(g4[tid]), fg = fsig(g4[tid + 256]);
      float gg = ftanh(g4[tid + 512]), og = fsig(g4[tid + 768]);
      c1r = fmaf(fg, c1r, ig * gg);
      float h1 = og * ftanh(c1r);
      h1s[tid] = h1;
      g4[tid] = h1 * wout_r;
    }
    __syncthreads();
    if (tid < 64) {
      float v = g4[tid] + g4[tid + 64] + g4[tid + 128] + g4[tid + 192];
#pragma unroll
      for (int off = 32; off > 0; off >>= 1) v += __shfl_down(v, off);
      if (tid == 0) {
        float pred = v + bo;
        float d = seq[b * kT + t] - pred;
        lacc = fmaf(d, d, lacc);
        xs_s = pred;
      }
    }
    __syncthreads();
  }
  if (tid == 0) atomicAdd(loss_out, lacc * (1.0f / (float)(kB * kT)));
}

}  // namespace

extern "C" void kernel_launch(void* const* d_in, const int* in_sizes, int n_in,
                              void* d_out, int out_size, void* d_ws, size_t ws_size,
                              hipStream_t stream) {
  const float* seq = (const float*)d_in[0];
  const float* z = (const float*)d_in[1];
  const float* wih0 = (const float*)d_in[3];
  const float* whh0 = (const float*)d_in[4];
  const float* bih0 = (const float*)d_in[5];
  const float* bhh0 = (const float*)d_in[6];
  const float* wih1 = (const float*)d_in[7];
  const float* whh1 = (const float*)d_in[8];
  const float* bih1 = (const float*)d_in[9];
  const float* bhh1 = (const float*)d_in[10];
  const float* wout = (const float*)d_in[11];
  const float* bout = (const float*)d_in[12];
  float* out = (float*)d_out;

  hipMemsetAsync(out, 0, sizeof(float), stream);

  if (ws_size >= kWsNeeded) {
    v8h* wpk = (v8h*)d_ws;
    pack_frag<<<384, 256, 0, stream>>>(whh0, wih1, whh1, wpk);
    decoder_mfma<<<16, 1024, 0, stream>>>(seq, z, wih0, bih0, bhh0, bih1, bhh1,
                                          wout, bout, wpk, out);
  } else {
    decoder_fallback<<<kB, 1024, 0, stream>>>(seq, z, wih0, bih0, bhh0, whh0,
                                              wih1, whh1, bih1, bhh1, wout, bout,
                                              out);
  }
}